// Round 12
// baseline (250.610 us; speedup 1.0000x reference)
//
#include <hip/hip_runtime.h>
#include <hip/hip_bf16.h>
#include <math.h>

#define IN_CH 256
#define HID 128
#define OUT_CH 64
#define MAXB 128          // max buckets (N <= 131072)
#define CAP 18432         // rec capacity per bucket (mean 16384, +16 sigma)
#define TILE 8192         // edges per bucket_kernel block

typedef __attribute__((ext_vector_type(8))) short bf16x8;
typedef __attribute__((ext_vector_type(4))) float f32x4;

// ---------------- bf16 pack/unpack helpers ----------------------------------
__device__ __forceinline__ unsigned int pack_bf2(float a, float b) {
    __hip_bfloat162 h = __float22bfloat162_rn(make_float2(a, b));
    return *(unsigned int*)&h;
}
__device__ __forceinline__ float2 bf2_to_f2(unsigned int v) {
    float2 r;
    r.x = __uint_as_float(v << 16);
    r.y = __uint_as_float(v & 0xffff0000u);
    return r;
}
__device__ __forceinline__ unsigned short f_to_bf1(float f) {
    __hip_bfloat16 h = __float2bfloat16(f);
    return *(unsigned short*)&h;
}

// ---------------- edge-index dtype detection (int32 vs int64) --------------
__global__ void detect_kernel(const void* ei, int E, int N, int* flag) {
    const long long* p = (const long long*)ei;
    int ok = 1;
    for (int j = 0; j < 16; ++j) {
        long long v = p[j];
        if (v < 0 || v >= (long long)N) { ok = 0; break; }
    }
    *flag = ok;
}

__device__ __forceinline__ int edge_at(const void* ei, long long pos, bool is64) {
    return is64 ? (int)((const long long*)ei)[pos] : ((const int*)ei)[pos];
}

// ---------------- W transpose + bf16 convert: wT1[n][k], wT2[n][k] ----------
__global__ __launch_bounds__(256) void wprep_kernel(const float* __restrict__ W1,
                                                    const float* __restrict__ W2,
                                                    unsigned short* __restrict__ wT1,
                                                    unsigned short* __restrict__ wT2) {
    int t = blockIdx.x * 256 + threadIdx.x;
    if (t < IN_CH * HID) {              // W1 [256][128] -> wT1 [128][256]
        int k = t >> 7, n = t & 127;
        wT1[n * IN_CH + k] = f_to_bf1(W1[t]);
    }
    if (t < HID * OUT_CH) {             // W2 [128][64] -> wT2 [64][128]
        int k = t >> 6, n = t & 63;
        wT2[n * HID + k] = f_to_bf1(W2[t]);
    }
}

// ---------------- level 1: block counting-sort of edges into buckets --------
__global__ __launch_bounds__(256) void bucket_kernel(const void* ei, int E, int B,
                                                     const int* __restrict__ flag,
                                                     unsigned int* __restrict__ recs,
                                                     int* __restrict__ bcur) {
    __shared__ int cnt[MAXB], off[MAXB], cur[MAXB], gb[MAXB];
    __shared__ unsigned int staged[TILE];
    const bool is64 = (*flag != 0);
    const int t = threadIdx.x;
    const long long base = (long long)blockIdx.x * TILE;

    for (int b = t; b < MAXB; b += 256) cnt[b] = 0;
    __syncthreads();

    for (int i = t; i < TILE; i += 256) {
        long long e = base + i;
        if (e < E) {
            int c = edge_at(ei, (long long)E + e, is64);
            atomicAdd(&cnt[c >> 10], 1);
        }
    }
    __syncthreads();

    if (t < MAXB) off[t] = cnt[t];
    __syncthreads();
    for (int o = 1; o < MAXB; o <<= 1) {
        int v = 0;
        if (t < MAXB && t >= o) v = off[t - o];
        __syncthreads();
        if (t < MAXB) off[t] += v;
        __syncthreads();
    }
    if (t < MAXB) {
        int ex = off[t] - cnt[t];
        off[t] = ex;
        cur[t] = ex;
        gb[t] = 0;
        if (t < B && cnt[t] > 0) gb[t] = atomicAdd(&bcur[t], cnt[t]);
    }
    __syncthreads();

    for (int i = t; i < TILE; i += 256) {
        long long e = base + i;
        if (e < E) {
            int r = edge_at(ei, e, is64);
            int c = edge_at(ei, (long long)E + e, is64);
            int b = c >> 10;
            int p = atomicAdd(&cur[b], 1);
            staged[p] = ((unsigned int)r << 10) | (unsigned int)(c & 1023);
        }
    }
    __syncthreads();

    int wv = t >> 6, ln = t & 63;
    for (int b = wv; b < B; b += 4) {
        int s = off[b];
        int n = cnt[b];
        int gbase = gb[b];
        if (gbase + n > CAP) n = (CAP > gbase) ? (CAP - gbase) : 0;
        for (int j = ln; j < n; j += 64)
            recs[(size_t)b * CAP + gbase + j] = staged[s + j];
    }
}

// ---------------- level 2: per-bucket CSR finalize (plain R8 form) -----------
__global__ __launch_bounds__(512) void csr_kernel(unsigned int* __restrict__ recs,
                                                  const int* __restrict__ bcur,
                                                  int* __restrict__ starts,
                                                  int* __restrict__ cnts,
                                                  float* __restrict__ dinv, int N) {
    __shared__ int degs[1024], lcur[1024], part[512];
    __shared__ unsigned int rows[CAP];
    const int b = blockIdx.x, t = threadIdx.x;
    const int n = min(bcur[b], CAP);
    const size_t rb = (size_t)b * CAP;

    degs[t] = 0;
    degs[t + 512] = 0;
    __syncthreads();
    for (int i = t; i < n; i += 512)
        atomicAdd(&degs[recs[rb + i] & 1023], 1);
    __syncthreads();

    int s0 = degs[2 * t], s1 = degs[2 * t + 1];
    part[t] = s0 + s1;
    __syncthreads();
    for (int o = 1; o < 512; o <<= 1) {
        int v = (t >= o) ? part[t - o] : 0;
        __syncthreads();
        part[t] += v;
        __syncthreads();
    }
    int ex = part[t] - (s0 + s1);
    lcur[2 * t] = ex;
    lcur[2 * t + 1] = ex + s0;

    int node = (b << 10) + 2 * t;
    if (node < N) {
        starts[node] = b * CAP + ex;
        cnts[node] = s0;
        dinv[node] = rsqrtf((float)(s0 + 1));
    }
    if (node + 1 < N) {
        starts[node + 1] = b * CAP + ex + s0;
        cnts[node + 1] = s1;
        dinv[node + 1] = rsqrtf((float)(s1 + 1));
    }
    __syncthreads();

    for (int i = t; i < n; i += 512) {
        unsigned int rc = recs[rb + i];
        int p = atomicAdd(&lcur[rc & 1023], 1);
        rows[p] = rc >> 10;
    }
    __syncthreads();
    for (int i = t; i < n; i += 512) recs[rb + i] = rows[i];
}

// ---------------- GEMM1 (MFMA bf16): u1c = bf16(dinv ⊙ (x @ W1)) ------------
// Output CHUNK-MAJOR: u1c[chunk=0..7][node][16ch] (ushort), chunk = nf.
__global__ __launch_bounds__(256) void gemm1_kernel(const float* __restrict__ x,
                                                    const unsigned short* __restrict__ wT,
                                                    const float* __restrict__ dinv,
                                                    unsigned short* __restrict__ u, int N) {
    __shared__ uint4 lds4[2048];  // 32 KB: As @0 (16 KB), Bs @16384 (16 KB)
    unsigned char* lds = (unsigned char*)lds4;
    const int t = threadIdx.x;
    const int bm0 = blockIdx.x * 128;
    const int wid = t >> 6, lane = t & 63;
    const int l16 = lane & 15, lq = lane >> 4;

    f32x4 acc[2][8];
#pragma unroll
    for (int mf = 0; mf < 2; ++mf)
#pragma unroll
        for (int nf = 0; nf < 8; ++nf) acc[mf][nf] = (f32x4){0.f, 0.f, 0.f, 0.f};

    for (int kc = 0; kc < IN_CH; kc += 64) {
#pragma unroll
        for (int it = 0; it < 4; ++it) {
            int uu = it * 256 + t;
            int r = uu >> 3, c8 = uu & 7;
            int row = bm0 + r;
            float4 v0 = make_float4(0.f, 0.f, 0.f, 0.f), v1 = v0;
            if (row < N) {
                const float* p = &x[(long long)row * IN_CH + kc + c8 * 8];
                v0 = *(const float4*)p;
                v1 = *(const float4*)(p + 4);
            }
            uint4 w;
            w.x = pack_bf2(v0.x, v0.y);
            w.y = pack_bf2(v0.z, v0.w);
            w.z = pack_bf2(v1.x, v1.y);
            w.w = pack_bf2(v1.z, v1.w);
            int off = (r * 128 + c8 * 16) ^ ((r & 7) << 4);
            *(uint4*)&lds[off] = w;
        }
#pragma unroll
        for (int it = 0; it < 4; ++it) {
            int uu = it * 256 + t;
            int n = uu >> 3, c8 = uu & 7;
            uint4 w = *(const uint4*)&wT[n * IN_CH + kc + c8 * 8];
            int off = 16384 + ((n * 128 + c8 * 16) ^ ((n & 7) << 4));
            *(uint4*)&lds[off] = w;
        }
        __syncthreads();
#pragma unroll
        for (int kk = 0; kk < 2; ++kk) {
            int kbyte = kk * 64 + lq * 16;
            bf16x8 a[2], b[8];
#pragma unroll
            for (int mf = 0; mf < 2; ++mf) {
                int r = wid * 32 + mf * 16 + l16;
                int off = (r * 128 + kbyte) ^ ((r & 7) << 4);
                a[mf] = *(const bf16x8*)&lds[off];
            }
#pragma unroll
            for (int nf = 0; nf < 8; ++nf) {
                int n = nf * 16 + l16;
                int off = 16384 + ((n * 128 + kbyte) ^ ((n & 7) << 4));
                b[nf] = *(const bf16x8*)&lds[off];
            }
#pragma unroll
            for (int mf = 0; mf < 2; ++mf)
#pragma unroll
                for (int nf = 0; nf < 8; ++nf)
                    acc[mf][nf] = __builtin_amdgcn_mfma_f32_16x16x32_bf16(
                        a[mf], b[nf], acc[mf][nf], 0, 0, 0);
        }
        __syncthreads();
    }
#pragma unroll
    for (int mf = 0; mf < 2; ++mf) {
#pragma unroll
        for (int j = 0; j < 4; ++j) {
            int row = bm0 + wid * 32 + mf * 16 + lq * 4 + j;
            if (row < N) {
                float dv = dinv[row];
#pragma unroll
                for (int nf = 0; nf < 8; ++nf)
                    u[((size_t)nf * N + row) * 16 + l16] = f_to_bf1(acc[mf][nf][j] * dv);
            }
        }
    }
}

// ---------------- GEMM2 (MFMA bf16): u2c = bf16(dinv ⊙ (hagg @ W2)) ---------
// A (hagg) is CHUNK-MAJOR [8][N][16ch]; output u2c chunk-major [4][N][16ch].
__global__ __launch_bounds__(256) void gemm2_kernel(const unsigned short* __restrict__ A,
                                                    const unsigned short* __restrict__ wT,
                                                    const float* __restrict__ dinv,
                                                    unsigned short* __restrict__ u, int N) {
    __shared__ uint4 lds4[1536];  // 24 KB
    unsigned char* lds = (unsigned char*)lds4;
    const int t = threadIdx.x;
    const int bm0 = blockIdx.x * 128;
    const int wid = t >> 6, lane = t & 63;
    const int l16 = lane & 15, lq = lane >> 4;

    f32x4 acc[2][4];
#pragma unroll
    for (int mf = 0; mf < 2; ++mf)
#pragma unroll
        for (int nf = 0; nf < 4; ++nf) acc[mf][nf] = (f32x4){0.f, 0.f, 0.f, 0.f};

    for (int kc = 0; kc < HID; kc += 64) {
#pragma unroll
        for (int it = 0; it < 4; ++it) {
            int uu = it * 256 + t;
            int r = uu >> 3, c8 = uu & 7;
            int row = bm0 + r;
            uint4 w = make_uint4(0, 0, 0, 0);
            if (row < N) {
                int chunk = (kc >> 4) + (c8 >> 1);   // abs channel / 16
                const unsigned short* Ac = A + (size_t)chunk * N * 16;
                w = *(const uint4*)&Ac[(size_t)row * 16 + (c8 & 1) * 8];
            }
            int off = (r * 128 + c8 * 16) ^ ((r & 7) << 4);
            *(uint4*)&lds[off] = w;
        }
#pragma unroll
        for (int it = 0; it < 2; ++it) {
            int uu = it * 256 + t;
            int n = uu >> 3, c8 = uu & 7;
            uint4 w = *(const uint4*)&wT[n * HID + kc + c8 * 8];
            int off = 16384 + ((n * 128 + c8 * 16) ^ ((n & 7) << 4));
            *(uint4*)&lds[off] = w;
        }
        __syncthreads();
#pragma unroll
        for (int kk = 0; kk < 2; ++kk) {
            int kbyte = kk * 64 + lq * 16;
            bf16x8 a[2], b[4];
#pragma unroll
            for (int mf = 0; mf < 2; ++mf) {
                int r = wid * 32 + mf * 16 + l16;
                int off = (r * 128 + kbyte) ^ ((r & 7) << 4);
                a[mf] = *(const bf16x8*)&lds[off];
            }
#pragma unroll
            for (int nf = 0; nf < 4; ++nf) {
                int n = nf * 16 + l16;
                int off = 16384 + ((n * 128 + kbyte) ^ ((n & 7) << 4));
                b[nf] = *(const bf16x8*)&lds[off];
            }
#pragma unroll
            for (int mf = 0; mf < 2; ++mf)
#pragma unroll
                for (int nf = 0; nf < 4; ++nf)
                    acc[mf][nf] = __builtin_amdgcn_mfma_f32_16x16x32_bf16(
                        a[mf], b[nf], acc[mf][nf], 0, 0, 0);
        }
        __syncthreads();
    }
#pragma unroll
    for (int mf = 0; mf < 2; ++mf) {
#pragma unroll
        for (int j = 0; j < 4; ++j) {
            int row = bm0 + wid * 32 + mf * 16 + lq * 4 + j;
            if (row < N) {
                float dv = dinv[row];
#pragma unroll
                for (int nf = 0; nf < 4; ++nf)
                    u[((size_t)nf * N + row) * 16 + l16] = f_to_bf1(acc[mf][nf][j] * dv);
            }
        }
    }
}

// ---------------- Agg1 (chunked): blockIdx.y = chunk (0..7) ------------------
// Table slice u1c[c] = N x 32 B = 3.2 MB -> L2-resident per XCD. 8 lanes/node,
// 4 B/lane (2 ch). hagg chunk-major out. Per-channel sum order == edge order.
__global__ __launch_bounds__(256) void agg1_kernel(const unsigned int* __restrict__ u,
                                                   const int* __restrict__ starts,
                                                   const int* __restrict__ cnts,
                                                   const unsigned int* __restrict__ srow,
                                                   const float* __restrict__ dinv,
                                                   const float* __restrict__ bias,
                                                   unsigned int* __restrict__ out, int N) {
    const int c = blockIdx.y;
    const int g = threadIdx.x >> 3, k = threadIdx.x & 7;
    int node = blockIdx.x * 32 + g;
    bool act = node < N;
    int nd = act ? node : N - 1;
    const unsigned int* tab = u + (size_t)c * N * 8;

    float2 s = bf2_to_f2(tab[(size_t)nd * 8 + k]);  // self-loop term
    int beg = starts[nd];
    int cnt = act ? cnts[nd] : 0;
    int j = 0;
    for (; j + 7 < cnt; j += 8) {
        unsigned int gv[8];
#pragma unroll
        for (int q = 0; q < 8; ++q)
            gv[q] = tab[(size_t)(int)srow[beg + j + q] * 8 + k];
#pragma unroll
        for (int q = 0; q < 8; ++q) {
            float2 v = bf2_to_f2(gv[q]);
            s.x += v.x;
            s.y += v.y;
        }
    }
    if (j + 3 < cnt) {
        unsigned int gv[4];
#pragma unroll
        for (int q = 0; q < 4; ++q)
            gv[q] = tab[(size_t)(int)srow[beg + j + q] * 8 + k];
#pragma unroll
        for (int q = 0; q < 4; ++q) {
            float2 v = bf2_to_f2(gv[q]);
            s.x += v.x;
            s.y += v.y;
        }
        j += 4;
    }
    for (; j < cnt; ++j) {
        float2 v = bf2_to_f2(tab[(size_t)(int)srow[beg + j] * 8 + k]);
        s.x += v.x;
        s.y += v.y;
    }

    if (act) {
        float dv = dinv[nd];
        float2 bb = *(const float2*)&bias[c * 16 + k * 2];
        float ox = fmaxf(fmaf(dv, s.x, bb.x), 0.f);
        float oy = fmaxf(fmaf(dv, s.y, bb.y), 0.f);
        out[(size_t)c * N * 8 + (size_t)node * 8 + k] = pack_bf2(ox, oy);
    }
}

// ---------------- Agg2 (chunked): blockIdx.y = chunk (0..3) ------------------
// u2c[c] = 3.2 MB slice; output fp32 [N][64] (harness layout).
__global__ __launch_bounds__(256) void agg2_kernel(const unsigned int* __restrict__ u,
                                                   const int* __restrict__ starts,
                                                   const int* __restrict__ cnts,
                                                   const unsigned int* __restrict__ srow,
                                                   const float* __restrict__ dinv,
                                                   const float* __restrict__ bias,
                                                   float* __restrict__ out, int N) {
    const int c = blockIdx.y;
    const int g = threadIdx.x >> 3, k = threadIdx.x & 7;
    int node = blockIdx.x * 32 + g;
    bool act = node < N;
    int nd = act ? node : N - 1;
    const unsigned int* tab = u + (size_t)c * N * 8;

    float2 s = bf2_to_f2(tab[(size_t)nd * 8 + k]);  // self-loop term
    int beg = starts[nd];
    int cnt = act ? cnts[nd] : 0;
    int j = 0;
    for (; j + 7 < cnt; j += 8) {
        unsigned int gv[8];
#pragma unroll
        for (int q = 0; q < 8; ++q)
            gv[q] = tab[(size_t)(int)srow[beg + j + q] * 8 + k];
#pragma unroll
        for (int q = 0; q < 8; ++q) {
            float2 v = bf2_to_f2(gv[q]);
            s.x += v.x;
            s.y += v.y;
        }
    }
    if (j + 3 < cnt) {
        unsigned int gv[4];
#pragma unroll
        for (int q = 0; q < 4; ++q)
            gv[q] = tab[(size_t)(int)srow[beg + j + q] * 8 + k];
#pragma unroll
        for (int q = 0; q < 4; ++q) {
            float2 v = bf2_to_f2(gv[q]);
            s.x += v.x;
            s.y += v.y;
        }
        j += 4;
    }
    for (; j < cnt; ++j) {
        float2 v = bf2_to_f2(tab[(size_t)(int)srow[beg + j] * 8 + k]);
        s.x += v.x;
        s.y += v.y;
    }

    if (act) {
        float dv = dinv[nd];
        float2 bb = *(const float2*)&bias[c * 16 + k * 2];
        float2 o;
        o.x = fmaf(dv, s.x, bb.x);
        o.y = fmaf(dv, s.y, bb.y);
        *(float2*)&out[(size_t)node * OUT_CH + c * 16 + k * 2] = o;
    }
}

extern "C" void kernel_launch(void* const* d_in, const int* in_sizes, int n_in,
                              void* d_out, int out_size, void* d_ws, size_t ws_size,
                              hipStream_t stream) {
    const float* x  = (const float*)d_in[0];
    const void*  ei = d_in[1];
    const float* W1 = (const float*)d_in[2];
    const float* b1 = (const float*)d_in[3];
    const float* W2 = (const float*)d_in[4];
    const float* b2 = (const float*)d_in[5];
    float* out = (float*)d_out;

    const int N = in_sizes[0] / IN_CH;   // 100000
    const int E = in_sizes[1] / 2;       // 1600000
    const int B = (N + 1023) >> 10;      // 98 buckets

    char* ws = (char*)d_ws;
    size_t off = 0;
    auto alloc = [&](size_t bytes) -> void* {
        void* p = ws + off;
        off += (bytes + 255) & ~(size_t)255;
        return p;
    };
    int*            flag   = (int*)alloc(256);
    int*            bcur   = (int*)alloc(MAXB * 4);
    int*            starts = (int*)alloc((size_t)N * 4);
    int*            cnts   = (int*)alloc((size_t)N * 4);
    float*          dinv   = (float*)alloc((size_t)N * 4);
    unsigned int*   recs   = (unsigned int*)alloc((size_t)B * CAP * 4);
    unsigned short* wT1    = (unsigned short*)alloc((size_t)IN_CH * HID * 2);
    unsigned short* wT2    = (unsigned short*)alloc((size_t)HID * OUT_CH * 2);
    unsigned short* u1     = (unsigned short*)alloc((size_t)N * HID * 2);    // chunk-major [8][N][16]
    unsigned short* hagg   = (unsigned short*)alloc((size_t)N * HID * 2);    // chunk-major [8][N][16]
    unsigned short* u2     = (unsigned short*)alloc((size_t)N * OUT_CH * 2); // chunk-major [4][N][16]

    (void)hipMemsetAsync(bcur, 0, MAXB * 4, stream);
    detect_kernel<<<1, 1, 0, stream>>>(ei, E, N, flag);
    wprep_kernel<<<128, 256, 0, stream>>>(W1, W2, wT1, wT2);
    int tblocks = (E + TILE - 1) / TILE;  // 196
    bucket_kernel<<<tblocks, 256, 0, stream>>>(ei, E, B, flag, recs, bcur);
    csr_kernel<<<B, 512, 0, stream>>>(recs, bcur, starts, cnts, dinv, N);

    int gblocks = (N + 127) / 128;
    int nblocks32 = (N + 31) / 32;
    gemm1_kernel<<<gblocks, 256, 0, stream>>>(x, wT1, dinv, u1, N);
    agg1_kernel<<<dim3(nblocks32, 8), 256, 0, stream>>>(
        (const unsigned int*)u1, starts, cnts, recs, dinv, b1,
        (unsigned int*)hagg, N);
    gemm2_kernel<<<gblocks, 256, 0, stream>>>(hagg, wT2, dinv, u2, N);
    agg2_kernel<<<dim3(nblocks32, 4), 256, 0, stream>>>(
        (const unsigned int*)u2, starts, cnts, recs, dinv, b2, out, N);
}

// Round 13
// 200.327 us; speedup vs baseline: 1.2510x; 1.2510x over previous
//
#include <hip/hip_runtime.h>
#include <hip/hip_bf16.h>
#include <math.h>

#define IN_CH 256
#define HID 128
#define OUT_CH 64
#define MAXB 128          // max buckets (N <= 131072)
#define CAP 18432         // rec capacity per bucket (mean 16384, +16 sigma)
#define TILE 8192         // edges per bucket_kernel block

typedef __attribute__((ext_vector_type(8))) short bf16x8;
typedef __attribute__((ext_vector_type(4))) float f32x4;

// ---------------- bf16 pack/unpack helpers ----------------------------------
__device__ __forceinline__ unsigned int pack_bf2(float a, float b) {
    __hip_bfloat162 h = __float22bfloat162_rn(make_float2(a, b));
    return *(unsigned int*)&h;
}
__device__ __forceinline__ float2 bf2_to_f2(unsigned int v) {
    float2 r;
    r.x = __uint_as_float(v << 16);
    r.y = __uint_as_float(v & 0xffff0000u);
    return r;
}
__device__ __forceinline__ unsigned short f_to_bf1(float f) {
    __hip_bfloat16 h = __float2bfloat16(f);
    return *(unsigned short*)&h;
}
// accumulate 8 bf16 channels (uint4) into two float4
__device__ __forceinline__ void acc8(float4& a, float4& b, uint4 w) {
    float2 p0 = bf2_to_f2(w.x), p1 = bf2_to_f2(w.y);
    float2 p2 = bf2_to_f2(w.z), p3 = bf2_to_f2(w.w);
    a.x += p0.x; a.y += p0.y; a.z += p1.x; a.w += p1.y;
    b.x += p2.x; b.y += p2.y; b.z += p3.x; b.w += p3.y;
}
// accumulate 4 bf16 channels (uint2) into float4
__device__ __forceinline__ void acc4(float4& a, uint2 w) {
    float2 p0 = bf2_to_f2(w.x), p1 = bf2_to_f2(w.y);
    a.x += p0.x; a.y += p0.y; a.z += p1.x; a.w += p1.y;
}

// ---------------- edge-index dtype detection (int32 vs int64) --------------
__global__ void detect_kernel(const void* ei, int E, int N, int* flag) {
    const long long* p = (const long long*)ei;
    int ok = 1;
    for (int j = 0; j < 16; ++j) {
        long long v = p[j];
        if (v < 0 || v >= (long long)N) { ok = 0; break; }
    }
    *flag = ok;
}

__device__ __forceinline__ int edge_at(const void* ei, long long pos, bool is64) {
    return is64 ? (int)((const long long*)ei)[pos] : ((const int*)ei)[pos];
}

// ---------------- W transpose + bf16 convert: wT1[n][k], wT2[n][k] ----------
__global__ __launch_bounds__(256) void wprep_kernel(const float* __restrict__ W1,
                                                    const float* __restrict__ W2,
                                                    unsigned short* __restrict__ wT1,
                                                    unsigned short* __restrict__ wT2) {
    int t = blockIdx.x * 256 + threadIdx.x;
    if (t < IN_CH * HID) {              // W1 [256][128] -> wT1 [128][256]
        int k = t >> 7, n = t & 127;
        wT1[n * IN_CH + k] = f_to_bf1(W1[t]);
    }
    if (t < HID * OUT_CH) {             // W2 [128][64] -> wT2 [64][128]
        int k = t >> 6, n = t & 63;
        wT2[n * HID + k] = f_to_bf1(W2[t]);
    }
}

// ---------------- level 1: block counting-sort of edges into buckets --------
__global__ __launch_bounds__(256) void bucket_kernel(const void* ei, int E, int B,
                                                     const int* __restrict__ flag,
                                                     unsigned int* __restrict__ recs,
                                                     int* __restrict__ bcur) {
    __shared__ int cnt[MAXB], off[MAXB], cur[MAXB], gb[MAXB];
    __shared__ unsigned int staged[TILE];
    const bool is64 = (*flag != 0);
    const int t = threadIdx.x;
    const long long base = (long long)blockIdx.x * TILE;

    for (int b = t; b < MAXB; b += 256) cnt[b] = 0;
    __syncthreads();

    for (int i = t; i < TILE; i += 256) {
        long long e = base + i;
        if (e < E) {
            int c = edge_at(ei, (long long)E + e, is64);
            atomicAdd(&cnt[c >> 10], 1);
        }
    }
    __syncthreads();

    if (t < MAXB) off[t] = cnt[t];
    __syncthreads();
    for (int o = 1; o < MAXB; o <<= 1) {
        int v = 0;
        if (t < MAXB && t >= o) v = off[t - o];
        __syncthreads();
        if (t < MAXB) off[t] += v;
        __syncthreads();
    }
    if (t < MAXB) {
        int ex = off[t] - cnt[t];
        off[t] = ex;
        cur[t] = ex;
        gb[t] = 0;
        if (t < B && cnt[t] > 0) gb[t] = atomicAdd(&bcur[t], cnt[t]);
    }
    __syncthreads();

    for (int i = t; i < TILE; i += 256) {
        long long e = base + i;
        if (e < E) {
            int r = edge_at(ei, e, is64);
            int c = edge_at(ei, (long long)E + e, is64);
            int b = c >> 10;
            int p = atomicAdd(&cur[b], 1);
            staged[p] = ((unsigned int)r << 10) | (unsigned int)(c & 1023);
        }
    }
    __syncthreads();

    int wv = t >> 6, ln = t & 63;
    for (int b = wv; b < B; b += 4) {
        int s = off[b];
        int n = cnt[b];
        int gbase = gb[b];
        if (gbase + n > CAP) n = (CAP > gbase) ? (CAP - gbase) : 0;
        for (int j = ln; j < n; j += 64)
            recs[(size_t)b * CAP + gbase + j] = staged[s + j];
    }
}

// ---------------- level 2: per-bucket CSR finalize ---------------------------
__global__ __launch_bounds__(512) void csr_kernel(unsigned int* __restrict__ recs,
                                                  const int* __restrict__ bcur,
                                                  int* __restrict__ starts,
                                                  int* __restrict__ cnts,
                                                  float* __restrict__ dinv, int N) {
    __shared__ int degs[1024], lcur[1024], part[512];
    __shared__ unsigned int rows[CAP];
    const int b = blockIdx.x, t = threadIdx.x;
    const int n = min(bcur[b], CAP);
    const size_t rb = (size_t)b * CAP;

    degs[t] = 0;
    degs[t + 512] = 0;
    __syncthreads();
    for (int i = t; i < n; i += 512)
        atomicAdd(&degs[recs[rb + i] & 1023], 1);
    __syncthreads();

    int s0 = degs[2 * t], s1 = degs[2 * t + 1];
    part[t] = s0 + s1;
    __syncthreads();
    for (int o = 1; o < 512; o <<= 1) {
        int v = (t >= o) ? part[t - o] : 0;
        __syncthreads();
        part[t] += v;
        __syncthreads();
    }
    int ex = part[t] - (s0 + s1);
    lcur[2 * t] = ex;
    lcur[2 * t + 1] = ex + s0;

    int node = (b << 10) + 2 * t;
    if (node < N) {
        starts[node] = b * CAP + ex;
        cnts[node] = s0;
        dinv[node] = rsqrtf((float)(s0 + 1));
    }
    if (node + 1 < N) {
        starts[node + 1] = b * CAP + ex + s0;
        cnts[node + 1] = s1;
        dinv[node + 1] = rsqrtf((float)(s1 + 1));
    }
    __syncthreads();

    for (int i = t; i < n; i += 512) {
        unsigned int rc = recs[rb + i];
        int p = atomicAdd(&lcur[rc & 1023], 1);
        rows[p] = rc >> 10;
    }
    __syncthreads();
    for (int i = t; i < n; i += 512) recs[rb + i] = rows[i];
}

// ---------------- GEMM1 (MFMA bf16): u1 = bf16(dinv ⊙ (x @ W1)) -------------
__global__ __launch_bounds__(256) void gemm1_kernel(const float* __restrict__ x,
                                                    const unsigned short* __restrict__ wT,
                                                    const float* __restrict__ dinv,
                                                    unsigned short* __restrict__ u, int N) {
    __shared__ uint4 lds4[2048];  // 32 KB: As @0 (16 KB), Bs @16384 (16 KB)
    unsigned char* lds = (unsigned char*)lds4;
    const int t = threadIdx.x;
    const int bm0 = blockIdx.x * 128;
    const int wid = t >> 6, lane = t & 63;
    const int l16 = lane & 15, lq = lane >> 4;

    f32x4 acc[2][8];
#pragma unroll
    for (int mf = 0; mf < 2; ++mf)
#pragma unroll
        for (int nf = 0; nf < 8; ++nf) acc[mf][nf] = (f32x4){0.f, 0.f, 0.f, 0.f};

    for (int kc = 0; kc < IN_CH; kc += 64) {
#pragma unroll
        for (int it = 0; it < 4; ++it) {
            int uu = it * 256 + t;
            int r = uu >> 3, c8 = uu & 7;
            int row = bm0 + r;
            float4 v0 = make_float4(0.f, 0.f, 0.f, 0.f), v1 = v0;
            if (row < N) {
                const float* p = &x[(long long)row * IN_CH + kc + c8 * 8];
                v0 = *(const float4*)p;
                v1 = *(const float4*)(p + 4);
            }
            uint4 w;
            w.x = pack_bf2(v0.x, v0.y);
            w.y = pack_bf2(v0.z, v0.w);
            w.z = pack_bf2(v1.x, v1.y);
            w.w = pack_bf2(v1.z, v1.w);
            int off = (r * 128 + c8 * 16) ^ ((r & 7) << 4);
            *(uint4*)&lds[off] = w;
        }
#pragma unroll
        for (int it = 0; it < 4; ++it) {
            int uu = it * 256 + t;
            int n = uu >> 3, c8 = uu & 7;
            uint4 w = *(const uint4*)&wT[n * IN_CH + kc + c8 * 8];
            int off = 16384 + ((n * 128 + c8 * 16) ^ ((n & 7) << 4));
            *(uint4*)&lds[off] = w;
        }
        __syncthreads();
#pragma unroll
        for (int kk = 0; kk < 2; ++kk) {
            int kbyte = kk * 64 + lq * 16;
            bf16x8 a[2], b[8];
#pragma unroll
            for (int mf = 0; mf < 2; ++mf) {
                int r = wid * 32 + mf * 16 + l16;
                int off = (r * 128 + kbyte) ^ ((r & 7) << 4);
                a[mf] = *(const bf16x8*)&lds[off];
            }
#pragma unroll
            for (int nf = 0; nf < 8; ++nf) {
                int n = nf * 16 + l16;
                int off = 16384 + ((n * 128 + kbyte) ^ ((n & 7) << 4));
                b[nf] = *(const bf16x8*)&lds[off];
            }
#pragma unroll
            for (int mf = 0; mf < 2; ++mf)
#pragma unroll
                for (int nf = 0; nf < 8; ++nf)
                    acc[mf][nf] = __builtin_amdgcn_mfma_f32_16x16x32_bf16(
                        a[mf], b[nf], acc[mf][nf], 0, 0, 0);
        }
        __syncthreads();
    }
#pragma unroll
    for (int mf = 0; mf < 2; ++mf) {
#pragma unroll
        for (int j = 0; j < 4; ++j) {
            int row = bm0 + wid * 32 + mf * 16 + lq * 4 + j;
            if (row < N) {
                float dv = dinv[row];
#pragma unroll
                for (int nf = 0; nf < 8; ++nf)
                    u[(long long)row * HID + nf * 16 + l16] = f_to_bf1(acc[mf][nf][j] * dv);
            }
        }
    }
}

// ---------------- GEMM2 (MFMA bf16): u2 = bf16(dinv ⊙ (hagg @ W2)) ----------
// A is bf16 [N][128] (written by agg1); staging is a direct uint4 copy.
__global__ __launch_bounds__(256) void gemm2_kernel(const unsigned short* __restrict__ A,
                                                    const unsigned short* __restrict__ wT,
                                                    const float* __restrict__ dinv,
                                                    unsigned short* __restrict__ u, int N) {
    __shared__ uint4 lds4[1536];  // 24 KB
    unsigned char* lds = (unsigned char*)lds4;
    const int t = threadIdx.x;
    const int bm0 = blockIdx.x * 128;
    const int wid = t >> 6, lane = t & 63;
    const int l16 = lane & 15, lq = lane >> 4;

    f32x4 acc[2][4];
#pragma unroll
    for (int mf = 0; mf < 2; ++mf)
#pragma unroll
        for (int nf = 0; nf < 4; ++nf) acc[mf][nf] = (f32x4){0.f, 0.f, 0.f, 0.f};

    for (int kc = 0; kc < HID; kc += 64) {
#pragma unroll
        for (int it = 0; it < 4; ++it) {
            int uu = it * 256 + t;
            int r = uu >> 3, c8 = uu & 7;
            int row = bm0 + r;
            uint4 w = make_uint4(0, 0, 0, 0);
            if (row < N) w = *(const uint4*)&A[(long long)row * HID + kc + c8 * 8];
            int off = (r * 128 + c8 * 16) ^ ((r & 7) << 4);
            *(uint4*)&lds[off] = w;
        }
#pragma unroll
        for (int it = 0; it < 2; ++it) {
            int uu = it * 256 + t;
            int n = uu >> 3, c8 = uu & 7;
            uint4 w = *(const uint4*)&wT[n * HID + kc + c8 * 8];
            int off = 16384 + ((n * 128 + c8 * 16) ^ ((n & 7) << 4));
            *(uint4*)&lds[off] = w;
        }
        __syncthreads();
#pragma unroll
        for (int kk = 0; kk < 2; ++kk) {
            int kbyte = kk * 64 + lq * 16;
            bf16x8 a[2], b[4];
#pragma unroll
            for (int mf = 0; mf < 2; ++mf) {
                int r = wid * 32 + mf * 16 + l16;
                int off = (r * 128 + kbyte) ^ ((r & 7) << 4);
                a[mf] = *(const bf16x8*)&lds[off];
            }
#pragma unroll
            for (int nf = 0; nf < 4; ++nf) {
                int n = nf * 16 + l16;
                int off = 16384 + ((n * 128 + kbyte) ^ ((n & 7) << 4));
                b[nf] = *(const bf16x8*)&lds[off];
            }
#pragma unroll
            for (int mf = 0; mf < 2; ++mf)
#pragma unroll
                for (int nf = 0; nf < 4; ++nf)
                    acc[mf][nf] = __builtin_amdgcn_mfma_f32_16x16x32_bf16(
                        a[mf], b[nf], acc[mf][nf], 0, 0, 0);
        }
        __syncthreads();
    }
#pragma unroll
    for (int mf = 0; mf < 2; ++mf) {
#pragma unroll
        for (int j = 0; j < 4; ++j) {
            int row = bm0 + wid * 32 + mf * 16 + lq * 4 + j;
            if (row < N) {
                float dv = dinv[row];
#pragma unroll
                for (int nf = 0; nf < 4; ++nf)
                    u[(long long)row * OUT_CH + nf * 16 + l16] = f_to_bf1(acc[mf][nf][j] * dv);
            }
        }
    }
}

// ---------------- Agg1: 4 nodes/wave, 16 lanes/node, uint4 (8 ch) per lane --
// hagg_bf16[i] = bf16(relu(dinv[i]*(u1[i] + Σ u1[row]) + b1)); unroll 8/4/1.
__global__ __launch_bounds__(256) void agg1_kernel(const uint4* __restrict__ u,
                                                   const int* __restrict__ starts,
                                                   const int* __restrict__ cnts,
                                                   const unsigned int* __restrict__ srow,
                                                   const float* __restrict__ dinv,
                                                   const float* __restrict__ bias,
                                                   unsigned short* __restrict__ out, int N) {
    int wave = threadIdx.x >> 6;
    int lane = threadIdx.x & 63;
    int q = lane >> 4, l16 = lane & 15;
    int node = blockIdx.x * 16 + wave * 4 + q;
    bool act = node < N;
    int nd = act ? node : N - 1;

    float4 sa = make_float4(0.f, 0.f, 0.f, 0.f), sb = sa;
    acc8(sa, sb, u[(size_t)nd * 16 + l16]);  // self-loop term

    int beg = starts[nd];
    int cnt = act ? cnts[nd] : 0;
    int j = 0;
    for (; j + 7 < cnt; j += 8) {
        uint4 g[8];
#pragma unroll
        for (int k = 0; k < 8; ++k)
            g[k] = u[(size_t)(int)srow[beg + j + k] * 16 + l16];
#pragma unroll
        for (int k = 0; k < 8; ++k) acc8(sa, sb, g[k]);
    }
    if (j + 3 < cnt) {
        uint4 g[4];
#pragma unroll
        for (int k = 0; k < 4; ++k)
            g[k] = u[(size_t)(int)srow[beg + j + k] * 16 + l16];
#pragma unroll
        for (int k = 0; k < 4; ++k) acc8(sa, sb, g[k]);
        j += 4;
    }
    for (; j < cnt; ++j)
        acc8(sa, sb, u[(size_t)(int)srow[beg + j] * 16 + l16]);

    if (act) {
        float dv = dinv[nd];
        float4 b0 = *(const float4*)&bias[l16 * 8];
        float4 b1v = *(const float4*)&bias[l16 * 8 + 4];
        float o0 = fmaxf(fmaf(dv, sa.x, b0.x), 0.f);
        float o1 = fmaxf(fmaf(dv, sa.y, b0.y), 0.f);
        float o2 = fmaxf(fmaf(dv, sa.z, b0.z), 0.f);
        float o3 = fmaxf(fmaf(dv, sa.w, b0.w), 0.f);
        float o4 = fmaxf(fmaf(dv, sb.x, b1v.x), 0.f);
        float o5 = fmaxf(fmaf(dv, sb.y, b1v.y), 0.f);
        float o6 = fmaxf(fmaf(dv, sb.z, b1v.z), 0.f);
        float o7 = fmaxf(fmaf(dv, sb.w, b1v.w), 0.f);
        uint4 w;
        w.x = pack_bf2(o0, o1);
        w.y = pack_bf2(o2, o3);
        w.z = pack_bf2(o4, o5);
        w.w = pack_bf2(o6, o7);
        *(uint4*)&out[(size_t)node * HID + l16 * 8] = w;
    }
}

// ---------------- Agg2: 4 nodes/wave, 16 lanes/node, uint2 (4 ch) per lane --
// out[i] = dinv[i]*(u2[i] + Σ u2[row]) + b2; unroll 8/4/1; output fp32.
__global__ __launch_bounds__(256) void agg2_kernel(const uint2* __restrict__ u,
                                                   const int* __restrict__ starts,
                                                   const int* __restrict__ cnts,
                                                   const unsigned int* __restrict__ srow,
                                                   const float* __restrict__ dinv,
                                                   const float* __restrict__ bias,
                                                   float* __restrict__ out, int N) {
    int wave = threadIdx.x >> 6;
    int lane = threadIdx.x & 63;
    int q = lane >> 4, l16 = lane & 15;
    int node = blockIdx.x * 16 + wave * 4 + q;
    bool act = node < N;
    int nd = act ? node : N - 1;

    float4 s = make_float4(0.f, 0.f, 0.f, 0.f);
    acc4(s, u[(size_t)nd * 16 + l16]);  // self-loop term

    int beg = starts[nd];
    int cnt = act ? cnts[nd] : 0;
    int j = 0;
    for (; j + 7 < cnt; j += 8) {
        uint2 g[8];
#pragma unroll
        for (int k = 0; k < 8; ++k)
            g[k] = u[(size_t)(int)srow[beg + j + k] * 16 + l16];
#pragma unroll
        for (int k = 0; k < 8; ++k) acc4(s, g[k]);
    }
    if (j + 3 < cnt) {
        uint2 g[4];
#pragma unroll
        for (int k = 0; k < 4; ++k)
            g[k] = u[(size_t)(int)srow[beg + j + k] * 16 + l16];
#pragma unroll
        for (int k = 0; k < 4; ++k) acc4(s, g[k]);
        j += 4;
    }
    for (; j < cnt; ++j)
        acc4(s, u[(size_t)(int)srow[beg + j] * 16 + l16]);

    if (act) {
        float dv = dinv[nd];
        float4 bb = *(const float4*)&bias[l16 * 4];
        float4 o;
        o.x = fmaf(dv, s.x, bb.x);
        o.y = fmaf(dv, s.y, bb.y);
        o.z = fmaf(dv, s.z, bb.z);
        o.w = fmaf(dv, s.w, bb.w);
        *(float4*)&out[(size_t)node * OUT_CH + l16 * 4] = o;
    }
}

extern "C" void kernel_launch(void* const* d_in, const int* in_sizes, int n_in,
                              void* d_out, int out_size, void* d_ws, size_t ws_size,
                              hipStream_t stream) {
    const float* x  = (const float*)d_in[0];
    const void*  ei = d_in[1];
    const float* W1 = (const float*)d_in[2];
    const float* b1 = (const float*)d_in[3];
    const float* W2 = (const float*)d_in[4];
    const float* b2 = (const float*)d_in[5];
    float* out = (float*)d_out;

    const int N = in_sizes[0] / IN_CH;   // 100000
    const int E = in_sizes[1] / 2;       // 1600000
    const int B = (N + 1023) >> 10;      // 98 buckets

    char* ws = (char*)d_ws;
    size_t off = 0;
    auto alloc = [&](size_t bytes) -> void* {
        void* p = ws + off;
        off += (bytes + 255) & ~(size_t)255;
        return p;
    };
    int*            flag   = (int*)alloc(256);
    int*            bcur   = (int*)alloc(MAXB * 4);
    int*            starts = (int*)alloc((size_t)N * 4);
    int*            cnts   = (int*)alloc((size_t)N * 4);
    float*          dinv   = (float*)alloc((size_t)N * 4);
    unsigned int*   recs   = (unsigned int*)alloc((size_t)B * CAP * 4);
    unsigned short* wT1    = (unsigned short*)alloc((size_t)IN_CH * HID * 2);
    unsigned short* wT2    = (unsigned short*)alloc((size_t)HID * OUT_CH * 2);
    unsigned short* u1     = (unsigned short*)alloc((size_t)N * HID * 2);
    unsigned short* hagg   = (unsigned short*)alloc((size_t)N * HID * 2);
    unsigned short* u2     = (unsigned short*)alloc((size_t)N * OUT_CH * 2);

    (void)hipMemsetAsync(bcur, 0, MAXB * 4, stream);
    detect_kernel<<<1, 1, 0, stream>>>(ei, E, N, flag);
    wprep_kernel<<<128, 256, 0, stream>>>(W1, W2, wT1, wT2);
    int tblocks = (E + TILE - 1) / TILE;  // 196
    bucket_kernel<<<tblocks, 256, 0, stream>>>(ei, E, B, flag, recs, bcur);
    csr_kernel<<<B, 512, 0, stream>>>(recs, bcur, starts, cnts, dinv, N);

    int gblocks = (N + 127) / 128;
    int ablocks = (N + 15) / 16;
    gemm1_kernel<<<gblocks, 256, 0, stream>>>(x, wT1, dinv, u1, N);
    agg1_kernel<<<ablocks, 256, 0, stream>>>((const uint4*)u1, starts, cnts, recs,
                                             dinv, b1, hagg, N);
    gemm2_kernel<<<gblocks, 256, 0, stream>>>(hagg, wT2, dinv, u2, N);
    agg2_kernel<<<ablocks, 256, 0, stream>>>((const uint2*)u2, starts, cnts, recs,
                                             dinv, b2, out, N);
}